// Round 8
// baseline (1072.083 us; speedup 1.0000x reference)
//
#include <hip/hip_runtime.h>
#include <math.h>

// Problem dims
#define NR    6144
#define DIM1  3000
#define DIM2  1000
#define HID   128
#define LATD  64
#define NEXP  16

typedef __bf16 bf16x8 __attribute__((ext_vector_type(8)));
typedef float  f32x4  __attribute__((ext_vector_type(4)));

// ================================================================
// f32 -> bf16 helpers
// ================================================================
__device__ __forceinline__ unsigned short f2bf_rne(float x) {
  unsigned u = __float_as_uint(x);
  u += 0x7FFFu + ((u >> 16) & 1u);
  return (unsigned short)(u >> 16);
}
__device__ __forceinline__ void split2(float v, unsigned short& h, unsigned short& l) {
  h = f2bf_rne(v);
  float hf = __uint_as_float((unsigned)h << 16);
  l = f2bf_rne(v - hf);
}
// packed 2xf32 -> 2xbf16 in one VALU op (v0 -> low16, v1 -> high16)
__device__ __forceinline__ unsigned cvt_pk_bf16(float a, float b) {
  unsigned r;
  asm("v_cvt_pk_bf16_f32 %0, %1, %2" : "=v"(r) : "v"(a), "v"(b));
  return r;
}

// ================================================================
// MFMA GEMM body. C[M,N](f32) (+)= A[M,K](f32, split on the fly) @ B
// B pre-split/transposed: BT_hi/BT_lo bf16 [N][Kpad].
// BM=128,BN=128,BK=32; 256 thr = 4 waves, wave tile 64x64.
// LDS: single 32KB buffer, 128B rows, 8x16B slots, slot^(row&7) swizzle.
// RAW s_barrier (no vmcnt drain!) + 2-deep A prefetch + 1-deep B:
//   flight(A) ~ 1.5 k-steps >= HBM latency; flight(B) ~ 1 step >= L2.
// Per substep s:
//   pack A(s)  [compiler-counted vmcnt wait]
//   SB0; s_barrier; SB0                  <- barrier1: prev reads done
//   ds_write A(s),B(s); lgkmcnt(0); SB0; s_barrier; SB0  <- barrier2
//   issue B(s+1); issue A(s+2)           <- fly across everything
//   ds_read; MFMA
// ================================================================
template<bool SPLIT3, bool ATOMIC>
__device__ __forceinline__ void gemm_body(
    unsigned short* __restrict__ bufA, unsigned short* __restrict__ bufB,
    const float* __restrict__ A,
    const unsigned short* __restrict__ BTh,
    const unsigned short* __restrict__ BTl,
    const float* __restrict__ bias,
    float* __restrict__ C,
    int M, int N, int K, int lda, int Kpad, int ldc,
    int bm, int bn, int k0, int kend)
{
  const int tid  = threadIdx.x;
  const int lane = tid & 63;
  const int wave = tid >> 6;
  const int wm = wave >> 1, wn = wave & 1;
  const int lrow = lane & 15, kg = lane >> 4;
  const int nsteps = (kend - k0 + 31) >> 5;

  f32x4 acc[4][4];
  #pragma unroll
  for (int f = 0; f < 4; ++f)
    #pragma unroll
    for (int g = 0; g < 4; ++g)
      #pragma unroll
      for (int j = 0; j < 4; ++j) acc[f][g][j] = 0.f;

  // staging: thread -> (row 0..127, k-half 0/16)
  const int srow = tid >> 1;
  const int ks   = (tid & 1) * 16;
  const int s0   = (tid & 1) * 2;      // logical 16B slot base: 0 or 2
  const float* aRow = A + (size_t)(bm + srow) * lda;
  const int gn = bn + srow;
  const bool bvalid = gn < N;
  const unsigned short* bRowH = BTh + (size_t)(bvalid ? gn : 0) * Kpad;
  const unsigned short* bRowL = SPLIT3 ? (BTl + (size_t)(bvalid ? gn : 0) * Kpad) : BTh;

  const int rx = srow & 7;
  const int wa0 = srow * 64 + (((s0 + 0) ^ rx) * 8);
  const int wa1 = srow * 64 + (((s0 + 1) ^ rx) * 8);
  const int wa2 = srow * 64 + (((s0 + 4) ^ rx) * 8);   // lo half (or B-hi if 1-pass)
  const int wa3 = srow * 64 + (((s0 + 5) ^ rx) * 8);

  // two named A prefetch sets (rule #20: no runtime-indexed arrays)
  float vaA[16], vaB[16];
  // single B prefetch set
  uint4 bh0 = make_uint4(0,0,0,0), bh1 = bh0, bl0 = bh0, bl1 = bh0;

  auto loadAinto = [&](float* va, int gk) {
    const int kb = gk + ks;
    if (kb + 16 <= kend) {
      const float4* ap = (const float4*)(aRow + kb);
      #pragma unroll
      for (int q = 0; q < 4; ++q) {
        float4 f4 = ap[q];
        va[4*q+0] = f4.x; va[4*q+1] = f4.y; va[4*q+2] = f4.z; va[4*q+3] = f4.w;
      }
    } else {
      #pragma unroll
      for (int i = 0; i < 16; ++i) va[i] = (kb + i < kend) ? aRow[kb + i] : 0.f;
    }
  };
  auto loadB = [&](int gk) {
    if (bvalid) {
      const uint4* bp = (const uint4*)(bRowH + gk + ks);
      bh0 = bp[0]; bh1 = bp[1];
      if (SPLIT3) {
        const uint4* bq = (const uint4*)(bRowL + gk + ks);
        bl0 = bq[0]; bl1 = bq[1];
      }
    }
  };

  auto substep = [&](float* va, int s) {
    // ---- pack A(s) (compiler-counted vmcnt; newer loads stay in flight) ----
    unsigned hw[8], lw[8];
    #pragma unroll
    for (int i = 0; i < 8; ++i) {
      hw[i] = cvt_pk_bf16(va[2*i], va[2*i+1]);
      if (SPLIT3) {
        const float h0 = __uint_as_float(hw[i] << 16);
        const float h1 = __uint_as_float(hw[i] & 0xFFFF0000u);
        lw[i] = cvt_pk_bf16(va[2*i] - h0, va[2*i+1] - h1);
      } else {
        lw[i] = 0;
      }
    }

    // ---- barrier1 (raw): all waves' MFMA reads of step s-1 complete ----
    __builtin_amdgcn_sched_barrier(0);
    __builtin_amdgcn_s_barrier();
    __builtin_amdgcn_sched_barrier(0);

    // ---- stage to LDS (B regs get counted vmcnt waits here) ----
    *(uint4*)&bufA[wa0] = make_uint4(hw[0], hw[1], hw[2], hw[3]);
    *(uint4*)&bufA[wa1] = make_uint4(hw[4], hw[5], hw[6], hw[7]);
    if (SPLIT3) {
      *(uint4*)&bufA[wa2] = make_uint4(lw[0], lw[1], lw[2], lw[3]);
      *(uint4*)&bufA[wa3] = make_uint4(lw[4], lw[5], lw[6], lw[7]);
      *(uint4*)&bufB[wa0] = bh0;
      *(uint4*)&bufB[wa1] = bh1;
      *(uint4*)&bufB[wa2] = bl0;
      *(uint4*)&bufB[wa3] = bl1;
    } else {
      *(uint4*)&bufA[wa2] = bh0;
      *(uint4*)&bufA[wa3] = bh1;
    }

    // ---- barrier2 (raw): writes visible; NO vmcnt drain ----
    asm volatile("s_waitcnt lgkmcnt(0)" ::: "memory");
    __builtin_amdgcn_sched_barrier(0);
    __builtin_amdgcn_s_barrier();
    __builtin_amdgcn_sched_barrier(0);

    // ---- issue next loads: B(s+1) 1-deep, A(s+2) 2-deep ----
    if (s + 1 < nsteps) loadB(k0 + (s + 1) * 32);
    if (s + 2 < nsteps) loadAinto(va, k0 + (s + 2) * 32);

    // ---- fragments (swizzled reads) + MFMA ----
    bf16x8 afh[4], bfh[4], afl[4], bfl[4];
    #pragma unroll
    for (int f = 0; f < 4; ++f) {
      const int r = wm * 64 + f * 16 + lrow;
      afh[f] = *(const bf16x8*)&bufA[r * 64 + ((kg ^ (r & 7)) * 8)];
      if (SPLIT3) afl[f] = *(const bf16x8*)&bufA[r * 64 + (((4 + kg) ^ (r & 7)) * 8)];
      const int n = wn * 64 + f * 16 + lrow;
      if (SPLIT3) {
        bfh[f] = *(const bf16x8*)&bufB[n * 64 + ((kg ^ (n & 7)) * 8)];
        bfl[f] = *(const bf16x8*)&bufB[n * 64 + (((4 + kg) ^ (n & 7)) * 8)];
      } else {
        bfh[f] = *(const bf16x8*)&bufA[n * 64 + (((4 + kg) ^ (n & 7)) * 8)];
      }
    }
    #pragma unroll
    for (int f = 0; f < 4; ++f)
      #pragma unroll
      for (int g = 0; g < 4; ++g) {
        acc[f][g] = __builtin_amdgcn_mfma_f32_16x16x32_bf16(afh[f], bfh[g], acc[f][g], 0, 0, 0);
        if constexpr (SPLIT3) {
          acc[f][g] = __builtin_amdgcn_mfma_f32_16x16x32_bf16(afl[f], bfh[g], acc[f][g], 0, 0, 0);
          acc[f][g] = __builtin_amdgcn_mfma_f32_16x16x32_bf16(afh[f], bfl[g], acc[f][g], 0, 0, 0);
        }
      }
  };

  // prologue: A(0), A(1) 2-deep; B(0) 1-deep
  loadAinto(vaA, k0);
  loadB(k0);
  if (nsteps > 1) loadAinto(vaB, k0 + 32);

  for (int s = 0; s < nsteps; ++s) {
    if ((s & 1) == 0) substep(vaA, s);
    else              substep(vaB, s);
  }

  // ---- epilogue: D col = lane&15, row = (lane>>4)*4 + j ----
  #pragma unroll
  for (int f = 0; f < 4; ++f) {
    #pragma unroll
    for (int g = 0; g < 4; ++g) {
      const int row0 = bm + wm * 64 + f * 16 + (lane >> 4) * 4;
      const int col  = bn + wn * 64 + g * 16 + (lane & 15);
      if (col < N) {
        #pragma unroll
        for (int j = 0; j < 4; ++j) {
          const size_t idx = (size_t)(row0 + j) * ldc + col;
          if (ATOMIC) atomicAdd(&C[idx], acc[f][g][j]);
          else        C[idx] = acc[f][g][j] + (bias ? bias[col] : 0.f);
        }
      }
    }
  }
}

template<bool SPLIT3, bool ATOMIC>
__global__ __launch_bounds__(256, 3) void gemm_mfma(
    const float* __restrict__ A,
    const unsigned short* __restrict__ BTh,
    const unsigned short* __restrict__ BTl,
    const float* __restrict__ bias,
    float* __restrict__ C,
    int M, int N, int K, int lda, int Kpad, int ldc, int kchunk)
{
  __shared__ alignas(16) unsigned short bufA[128 * 64];
  __shared__ alignas(16) unsigned short bufB[SPLIT3 ? 128 * 64 : 8];
  const int k0 = blockIdx.z * kchunk;
  gemm_body<SPLIT3, ATOMIC>(bufA, bufB, A, BTh, BTl, bias, C,
                            M, N, K, lda, Kpad, ldc,
                            blockIdx.x * 128, blockIdx.y * 128,
                            k0, min(k0 + kchunk, K));
}

// fused encoder: job0 = x1@W1 -> XW[:,0:128], job1 = x2@W2 -> XW[:,128:256]
__global__ __launch_bounds__(256, 3) void gemm_enc(
    const float* __restrict__ x1,
    const unsigned short* __restrict__ W1h, const unsigned short* __restrict__ W1l,
    const float* __restrict__ x2,
    const unsigned short* __restrict__ W2h, const unsigned short* __restrict__ W2l,
    float* __restrict__ XW)
{
  __shared__ alignas(16) unsigned short bufA[128 * 64];
  __shared__ alignas(16) unsigned short bufB[128 * 64];
  if (blockIdx.y == 0) {
    const int k0 = blockIdx.z * 376;
    gemm_body<true, true>(bufA, bufB, x1, W1h, W1l, nullptr, XW,
                          NR, HID, DIM1, DIM1, 3008, 256,
                          blockIdx.x * 128, 0, k0, min(k0 + 376, DIM1));
  } else {
    const int k0 = blockIdx.z * 128;
    gemm_body<true, true>(bufA, bufB, x2, W2h, W2l, nullptr, XW + HID,
                          NR, HID, DIM2, DIM2, 1024, 256,
                          blockIdx.x * 128, 0, k0, min(k0 + 128, DIM2));
  }
}

// ================================================================
// Transpose + hi/lo split: in f32 [K][N] -> out bf16 [N][Kpad]
// ================================================================
__global__ __launch_bounds__(256) void transpose_split(
    const float* __restrict__ in, unsigned short* __restrict__ out_hi,
    unsigned short* __restrict__ out_lo, int K, int N, int Kpad)
{
  __shared__ float tile[32][33];
  const int k0 = blockIdx.x * 32, n0 = blockIdx.y * 32;
  const int tx = threadIdx.x & 31, ty = threadIdx.x >> 5;
  #pragma unroll
  for (int r = 0; r < 4; ++r) {
    const int k = k0 + ty + r * 8;
    tile[ty + r * 8][tx] = (k < K && n0 + tx < N) ? in[(size_t)k * N + n0 + tx] : 0.f;
  }
  __syncthreads();
  #pragma unroll
  for (int r = 0; r < 4; ++r) {
    const int nn = ty + r * 8;
    const int n = n0 + nn, k = k0 + tx;
    if (n < N && k < Kpad) {
      unsigned short h, l;
      split2(tile[tx][nn], h, l);
      out_hi[(size_t)n * Kpad + k] = h;
      if (out_lo) out_lo[(size_t)n * Kpad + k] = l;
    }
  }
}

// ================================================================
// f32 tiled GEMM (fallback + small z@Wd)
// ================================================================
#define BM 64
#define BN 64
#define BK 16

__global__ __launch_bounds__(256) void gemm_f32(
    const float* __restrict__ A, const float* __restrict__ B,
    const float* __restrict__ bias, float* __restrict__ C,
    int M, int N, int K, int lda, int ldb, int ldc)
{
  __shared__ float At[BK][BM + 4];
  __shared__ float Bt[BK][BN + 4];
  const int tid = threadIdx.x;
  const int tx = tid & 15;
  const int ty = tid >> 4;
  const int bm = blockIdx.x * BM;
  const int bn = blockIdx.y * BN;

  float acc[4][4] = {};

  const int ar = tid >> 2;
  const int ak = (tid & 3) * 4;
  const int bk = tid >> 4;
  const int bc = (tid & 15) * 4;

  for (int k0 = 0; k0 < K; k0 += BK) {
    {
      float4 v = make_float4(0.f, 0.f, 0.f, 0.f);
      const int gr = bm + ar;
      const int gk = k0 + ak;
      if (gr < M && gk < K) {
        const float* p = &A[(size_t)gr * lda];
        if (gk + 3 < K) v = *reinterpret_cast<const float4*>(&p[gk]);
        else {
          v.x = p[gk];
          if (gk + 1 < K) v.y = p[gk + 1];
          if (gk + 2 < K) v.z = p[gk + 2];
        }
      }
      At[ak + 0][ar] = v.x; At[ak + 1][ar] = v.y;
      At[ak + 2][ar] = v.z; At[ak + 3][ar] = v.w;
    }
    {
      float4 v = make_float4(0.f, 0.f, 0.f, 0.f);
      const int gk = k0 + bk;
      const int gc = bn + bc;
      if (gk < K) {
        const float* p = &B[(size_t)gk * ldb];
        if (gc + 3 < N) v = *reinterpret_cast<const float4*>(&p[gc]);
        else {
          if (gc     < N) v.x = p[gc];
          if (gc + 1 < N) v.y = p[gc + 1];
          if (gc + 2 < N) v.z = p[gc + 2];
        }
      }
      *reinterpret_cast<float4*>(&Bt[bk][bc]) = v;
    }
    __syncthreads();
    #pragma unroll
    for (int kk = 0; kk < BK; ++kk) {
      float4 a4 = *reinterpret_cast<const float4*>(&At[kk][ty * 4]);
      float4 b4 = *reinterpret_cast<const float4*>(&Bt[kk][tx * 4]);
      float av[4] = {a4.x, a4.y, a4.z, a4.w};
      float bv[4] = {b4.x, b4.y, b4.z, b4.w};
      #pragma unroll
      for (int i = 0; i < 4; ++i)
        #pragma unroll
        for (int j = 0; j < 4; ++j)
          acc[i][j] = fmaf(av[i], bv[j], acc[i][j]);
    }
    __syncthreads();
  }

  #pragma unroll
  for (int i = 0; i < 4; ++i) {
    const int row = bm + ty * 4 + i;
    if (row >= M) continue;
    #pragma unroll
    for (int j = 0; j < 4; ++j) {
      const int col = bn + tx * 4 + j;
      if (col < N) {
        float v = acc[i][j];
        if (bias) v += bias[col];
        C[(size_t)row * ldc + col] = v;
      }
    }
  }
}

// ================================================================
// BN stats / fused heads+PoE / gating / loss  (verified round 2)
// ================================================================
__global__ __launch_bounds__(256) void bnstats_kernel(
    const float* __restrict__ H2, float* __restrict__ ssum, float* __restrict__ ssq)
{
  const int c = threadIdx.x;
  const int r0 = blockIdx.x * 12;
  float s = 0.f, q = 0.f;
  #pragma unroll
  for (int i = 0; i < 12; ++i) {
    float v = H2[(size_t)(r0 + i) * 256 + c];
    s += v;
    q = fmaf(v, v, q);
  }
  atomicAdd(&ssum[c], s);
  atomicAdd(&ssq[c], q);
}

__global__ __launch_bounds__(256) void mulv_kernel(
    const float* __restrict__ H2, const float* __restrict__ ssum, const float* __restrict__ ssq,
    const float* __restrict__ g1, const float* __restrict__ b1,
    const float* __restrict__ Wmu1, const float* __restrict__ bmu1,
    const float* __restrict__ Wlv1, const float* __restrict__ blv1,
    const float* __restrict__ g2, const float* __restrict__ b2,
    const float* __restrict__ Wmu2, const float* __restrict__ bmu2,
    const float* __restrict__ Wlv2, const float* __restrict__ blv2,
    float* __restrict__ pd_mu_out, float* __restrict__ pd_lv_out, float* __restrict__ z_out)
{
  __shared__ float hn[4][256];
  const int tid = threadIdx.x;
  const int r0 = blockIdx.x * 4;

  for (int idx = tid; idx < 1024; idx += 256) {
    const int rr = idx >> 8;
    const int c  = idx & 255;
    const float mean = ssum[c] * (1.0f / 6144.0f);
    const float var  = ssq[c] * (1.0f / 6144.0f) - mean * mean;
    const float rstd = 1.0f / sqrtf(var + 1e-5f);
    const float gamma = (c < HID) ? g1[c] : g2[c - HID];
    const float beta  = (c < HID) ? b1[c] : b2[c - HID];
    const float v = H2[(size_t)(r0 + rr) * 256 + c];
    hn[rr][c] = (v - mean) * rstd * gamma + beta;
  }
  __syncthreads();

  const int rr = tid >> 6;
  const int j  = tid & 63;
  float mu1 = bmu1[j], lv1 = blv1[j], mu2 = bmu2[j], lv2 = blv2[j];
  #pragma unroll 4
  for (int k = 0; k < HID; ++k) {
    const float h1 = hn[rr][k];
    const float h2 = hn[rr][HID + k];
    mu1 = fmaf(h1, Wmu1[k * LATD + j], mu1);
    lv1 = fmaf(h1, Wlv1[k * LATD + j], lv1);
    mu2 = fmaf(h2, Wmu2[k * LATD + j], mu2);
    lv2 = fmaf(h2, Wlv2[k * LATD + j], lv2);
  }
  const float var1 = expf(lv1) + 1e-8f;
  const float var2 = expf(lv2) + 1e-8f;
  const float T1 = 1.0f / (var1 + 1e-8f);
  const float T2 = 1.0f / (var2 + 1e-8f);
  const float denom = T1 + T2;
  const float pmu = (mu1 * T1 + mu2 * T2) / denom;
  const float plv = logf(1.0f / denom + 1e-8f);
  const size_t o = (size_t)(r0 + rr) * LATD + j;
  pd_mu_out[o] = pmu;
  pd_lv_out[o] = plv;
  z_out[o]     = pmu;
}

__device__ __forceinline__ unsigned rotl32(unsigned x, int r) {
  return (x << r) | (x >> (32 - r));
}

__device__ float threefry_normal(unsigned i) {
  const unsigned ks0 = 0u;
  const unsigned ks1 = 42u;
  const unsigned ks2 = 0x1BD11BDAu ^ 0u ^ 42u;
  unsigned x0 = 0u + ks0;
  unsigned x1 = i + ks1;

  #define TF_ROUND(r) { x0 += x1; x1 = rotl32(x1, r); x1 ^= x0; }
  TF_ROUND(13) TF_ROUND(15) TF_ROUND(26) TF_ROUND(6)
  x0 += ks1; x1 += ks2 + 1u;
  TF_ROUND(17) TF_ROUND(29) TF_ROUND(16) TF_ROUND(24)
  x0 += ks2; x1 += ks0 + 2u;
  TF_ROUND(13) TF_ROUND(15) TF_ROUND(26) TF_ROUND(6)
  x0 += ks0; x1 += ks1 + 3u;
  TF_ROUND(17) TF_ROUND(29) TF_ROUND(16) TF_ROUND(24)
  x0 += ks1; x1 += ks2 + 4u;
  TF_ROUND(13) TF_ROUND(15) TF_ROUND(26) TF_ROUND(6)
  x0 += ks2; x1 += ks0 + 5u;
  #undef TF_ROUND

  const unsigned bits = x0 ^ x1;

  const unsigned fb = (bits >> 9) | 0x3F800000u;
  const float u01 = __uint_as_float(fb) - 1.0f;
  const float minval = -0.99999994f;
  float u = fmaf(u01, 2.0f, minval);
  u = fmaxf(minval, u);

  float w = -log1pf(-u * u);
  float p;
  if (w < 5.0f) {
    w = w - 2.5f;
    p = 2.81022636e-08f;
    p = fmaf(p, w, 3.43273939e-07f);
    p = fmaf(p, w, -3.5233877e-06f);
    p = fmaf(p, w, -4.39150654e-06f);
    p = fmaf(p, w, 0.00021858087f);
    p = fmaf(p, w, -0.00125372503f);
    p = fmaf(p, w, -0.00417768164f);
    p = fmaf(p, w, 0.246640727f);
    p = fmaf(p, w, 1.50140941f);
  } else {
    w = sqrtf(w) - 3.0f;
    p = -0.000200214257f;
    p = fmaf(p, w, 0.000100950558f);
    p = fmaf(p, w, 0.00134934322f);
    p = fmaf(p, w, -0.00367342844f);
    p = fmaf(p, w, 0.00573950773f);
    p = fmaf(p, w, -0.0076224613f);
    p = fmaf(p, w, 0.00943887047f);
    p = fmaf(p, w, 1.00167406f);
    p = fmaf(p, w, 2.83297682f);
  }
  return 1.4142135f * (p * u);
}

__global__ __launch_bounds__(64) void gating_kernel(
    const float* __restrict__ z, const float* __restrict__ w_gate,
    const float* __restrict__ w_noise, float* __restrict__ gates_out,
    float* __restrict__ importance, float* __restrict__ loadv)
{
  __shared__ float zt[64][65];
  __shared__ float wg[64][16];
  __shared__ float wn[64][16];
  __shared__ float imp_s[16];
  __shared__ float load_s[16];

  const int tid = threadIdx.x;
  const int r0 = blockIdx.x * 64;

  for (int idx = tid; idx < 1024; idx += 64) {
    wg[idx >> 4][idx & 15] = w_gate[idx];
    wn[idx >> 4][idx & 15] = w_noise[idx];
  }
  for (int idx = tid; idx < 4096; idx += 64) {
    const int rr = idx >> 6, c = idx & 63;
    zt[rr][c] = z[(size_t)(r0 + rr) * 64 + c];
  }
  if (tid < 16) { imp_s[tid] = 0.f; load_s[tid] = 0.f; }
  __syncthreads();

  const int r = r0 + tid;
  float clean[16], noisy[16], stdv[16];
  #pragma unroll
  for (int e = 0; e < NEXP; ++e) {
    float c = 0.f, n = 0.f;
    #pragma unroll 8
    for (int k = 0; k < 64; ++k) {
      const float zv = zt[tid][k];
      c = fmaf(zv, wg[k][e], c);
      n = fmaf(zv, wn[k][e], n);
    }
    clean[e] = c;
    const float sp = fmaxf(n, 0.f) + log1pf(expf(-fabsf(n)));
    stdv[e] = sp + 0.01f;
    const float eps = threefry_normal((unsigned)r * 16u + (unsigned)e);
    noisy[e] = fmaf(eps, stdv[e], c);
  }

  float v0 = -1e30f, v1 = -1e30f, v2 = -1e30f;
  int i0 = 0, i1 = 0;
  #pragma unroll
  for (int e = 0; e < NEXP; ++e) {
    const float v = noisy[e];
    if (v > v0)      { v2 = v1; v1 = v0; i1 = i0; v0 = v; i0 = e; }
    else if (v > v1) { v2 = v1; v1 = v; i1 = e; }
    else if (v > v2) { v2 = v; }
  }

  const float e1 = expf(v1 - v0);
  const float inv = 1.0f / (1.0f + e1);
  const float g0 = inv;
  const float g1v = e1 * inv;

  float lacc[16];
  #pragma unroll
  for (int e = 0; e < NEXP; ++e) {
    const float gv = (e == i0) ? g0 : ((e == i1) ? g1v : 0.f);
    gates_out[(size_t)r * NEXP + e] = gv;
    const float thr = (noisy[e] > v2) ? v2 : v1;
    const float x = (clean[e] - thr) / stdv[e];
    lacc[e] = 0.5f * erfcf(-0.70710678f * x);
  }
  atomicAdd(&imp_s[i0], g0);
  atomicAdd(&imp_s[i1], g1v);
  #pragma unroll
  for (int e = 0; e < NEXP; ++e) atomicAdd(&load_s[e], lacc[e]);
  __syncthreads();
  if (tid < 16) {
    atomicAdd(&importance[tid], imp_s[tid]);
    atomicAdd(&loadv[tid], load_s[tid]);
  }
}

__global__ void loss_kernel(const float* __restrict__ imp, const float* __restrict__ ld,
                            float* __restrict__ out)
{
  if (threadIdx.x == 0 && blockIdx.x == 0) {
    float mi = 0.f, ml = 0.f;
    for (int e = 0; e < NEXP; ++e) { mi += imp[e]; ml += ld[e]; }
    mi *= (1.0f / 16.0f);
    ml *= (1.0f / 16.0f);
    float vi = 0.f, vl = 0.f;
    for (int e = 0; e < NEXP; ++e) {
      const float di = imp[e] - mi;
      const float dl = ld[e] - ml;
      vi = fmaf(di, di, vi);
      vl = fmaf(dl, dl, vl);
    }
    vi *= (1.0f / 15.0f);
    vl *= (1.0f / 15.0f);
    out[0] = vi / (mi * mi + 1e-10f) + vl / (ml * ml + 1e-10f);
  }
}

// ================================================================
extern "C" void kernel_launch(void* const* d_in, const int* in_sizes, int n_in,
                              void* d_out, int out_size, void* d_ws, size_t ws_size,
                              hipStream_t stream)
{
  const float* x1     = (const float*)d_in[0];
  const float* x2     = (const float*)d_in[1];
  const float* adj    = (const float*)d_in[2];
  const float* W1     = (const float*)d_in[3];
  const float* gamma1 = (const float*)d_in[4];
  const float* beta1  = (const float*)d_in[5];
  const float* Wmu1   = (const float*)d_in[6];
  const float* bmu1   = (const float*)d_in[7];
  const float* Wlv1   = (const float*)d_in[8];
  const float* blv1   = (const float*)d_in[9];
  const float* W2     = (const float*)d_in[10];
  const float* gamma2 = (const float*)d_in[11];
  const float* beta2  = (const float*)d_in[12];
  const float* Wmu2   = (const float*)d_in[13];
  const float* bmu2   = (const float*)d_in[14];
  const float* Wlv2   = (const float*)d_in[15];
  const float* blv2   = (const float*)d_in[16];
  const float* w_gate = (const float*)d_in[17];
  const float* w_noise= (const float*)d_in[18];
  const float* Wd1    = (const float*)d_in[19];
  const float* Wfc1   = (const float*)d_in[20];
  const float* bfc1   = (const float*)d_in[21];
  const float* Wd2    = (const float*)d_in[22];
  const float* Wfc2   = (const float*)d_in[23];
  const float* bfc2   = (const float*)d_in[24];

  float* out = (float*)d_out;
  float* recon1 = out;
  float* recon2 = out + (size_t)NR * DIM1;
  float* pd_mu  = recon2 + (size_t)NR * DIM2;
  float* pd_lv  = pd_mu + (size_t)NR * LATD;
  float* gates  = pd_lv + (size_t)NR * LATD;
  float* loss   = gates + (size_t)NR * NEXP;

  // ---------------- fast-path workspace layout (bytes) ----------------
  char* wsb = (char*)d_ws;
  const size_t o_XW   = 0;                      // f32 [6144][256]
  const size_t o_H2   = o_XW   + 6291456;       // f32 [6144][256]
  const size_t o_z    = o_H2   + 6291456;       // f32 [6144][64]
  const size_t o_ZD   = o_z    + 1572864;       // f32 [6144][128]
  const size_t o_AZ   = o_ZD   + 3145728;       // f32 [6144][128]
  const size_t o_XWTh = o_AZ   + 3145728;       // bf16 [256][6144]
  const size_t o_XWTl = o_XWTh + 3145728;
  const size_t o_W1Th = o_XWTl + 3145728;       // bf16 [128][3008]
  const size_t o_W1Tl = o_W1Th + 770048;
  const size_t o_W2Th = o_W1Tl + 770048;        // bf16 [128][1024]
  const size_t o_W2Tl = o_W2Th + 262144;
  const size_t o_ZDTh = o_W2Tl + 262144;        // bf16 [128][6144]
  const size_t o_F1Th = o_ZDTh + 1572864;       // bf16 [3000][64]
  const size_t o_F2Th = o_F1Th + 384000;        // bf16 [1000][64]
  const size_t o_stat = o_F2Th + 128000;        // 544 f32
  const size_t need   = o_stat + 2176;

  const dim3 blk(256);

  if (ws_size >= need) {
    // ================= fast path: bf16 MFMA =================
    float* XW   = (float*)(wsb + o_XW);
    float* H2   = (float*)(wsb + o_H2);
    float* zbuf = (float*)(wsb + o_z);
    float* ZD   = (float*)(wsb + o_ZD);
    float* AZ   = (float*)(wsb + o_AZ);
    unsigned short* XWTh = (unsigned short*)(wsb + o_XWTh);
    unsigned short* XWTl = (unsigned short*)(wsb + o_XWTl);
    unsigned short* W1Th = (unsigned short*)(wsb + o_W1Th);
    unsigned short* W1Tl = (unsigned short*)(wsb + o_W1Tl);
    unsigned short* W2Th = (unsigned short*)(wsb + o_W2Th);
    unsigned short* W2Tl = (unsigned short*)(wsb + o_W2Tl);
    unsigned short* ZDTh = (unsigned short*)(wsb + o_ZDTh);
    unsigned short* F1Th = (unsigned short*)(wsb + o_F1Th);
    unsigned short* F2Th = (unsigned short*)(wsb + o_F2Th);
    float* ssum = (float*)(wsb + o_stat);
    float* ssq  = ssum + 256;
    float* imp  = ssq + 256;
    float* ldv  = imp + 16;

    hipMemsetAsync(XW, 0, 6291456 * 2, stream);          // XW + H2
    hipMemsetAsync(AZ, 0, 3145728, stream);
    hipMemsetAsync(ssum, 0, 2176, stream);

    // pre-split weights (B operands, transposed [N][Kpad])
    transpose_split<<<dim3(94, 4), blk, 0, stream>>>(W1, W1Th, W1Tl, DIM1, HID, 3008);
    transpose_split<<<dim3(32, 4), blk, 0, stream>>>(W2, W2Th, W2Tl, DIM2, HID, 1024);
    transpose_split<<<dim3(2, 94), blk, 0, stream>>>(Wfc1, F1Th, nullptr, LATD, DIM1, 64);
    transpose_split<<<dim3(2, 32), blk, 0, stream>>>(Wfc2, F2Th, nullptr, LATD, DIM2, 64);

    // fused encoder: XW = [x1@W1 | x2@W2]  (3-pass, split-K=8)
    gemm_enc<<<dim3(48, 2, 8), blk, 0, stream>>>(x1, W1Th, W1Tl, x2, W2Th, W2Tl, XW);

    transpose_split<<<dim3(192, 8), blk, 0, stream>>>(XW, XWTh, XWTl, NR, 256, NR);

    // H2 = adj @ XW (3-pass, split-K=8)
    gemm_mfma<true, true><<<dim3(48, 2, 8), blk, 0, stream>>>(
        adj, XWTh, XWTl, nullptr, H2, NR, 256, NR, NR, NR, 256, 768);

    bnstats_kernel<<<512, blk, 0, stream>>>(H2, ssum, ssq);
    mulv_kernel<<<NR / 4, blk, 0, stream>>>(H2, ssum, ssq,
        gamma1, beta1, Wmu1, bmu1, Wlv1, blv1,
        gamma2, beta2, Wmu2, bmu2, Wlv2, blv2,
        pd_mu, pd_lv, zbuf);

    gating_kernel<<<NR / 64, 64, 0, stream>>>(zbuf, w_gate, w_noise, gates, imp, ldv);
    loss_kernel<<<1, 64, 0, stream>>>(imp, ldv, loss);

    // decoders
    gemm_f32<<<dim3(96, 1), blk, 0, stream>>>(zbuf, Wd1, nullptr, ZD,        NR, LATD, LATD, LATD, LATD, 128);
    gemm_f32<<<dim3(96, 1), blk, 0, stream>>>(zbuf, Wd2, nullptr, ZD + LATD, NR, LATD, LATD, LATD, LATD, 128);
    transpose_split<<<dim3(192, 4), blk, 0, stream>>>(ZD, ZDTh, nullptr, NR, 128, NR);
    gemm_mfma<false, true><<<dim3(48, 1, 16), blk, 0, stream>>>(
        adj, ZDTh, nullptr, nullptr, AZ, NR, 128, NR, NR, NR, 128, 384);
    gemm_mfma<false, false><<<dim3(48, 24, 1), blk, 0, stream>>>(
        AZ, F1Th, nullptr, bfc1, recon1, NR, DIM1, LATD, 128, 64, DIM1, 64);
    gemm_mfma<false, false><<<dim3(48, 8, 1), blk, 0, stream>>>(
        AZ + LATD, F2Th, nullptr, bfc2, recon2, NR, DIM2, LATD, 128, 64, DIM2, 64);
    return;
  }

  // ================= fallback: verified f32 path =================
  float* ws   = (float*)d_ws;
  float* XW   = ws;
  float* H2   = ws + 1572864;
  float* zbuf = ws + 3145728;
  float* ZD   = ws + 3538944;
  float* AZ   = ws + 4325376;
  float* ssum = ws + 5111808;
  float* ssq  = ws + 5112064;
  float* imp  = ws + 5112320;
  float* ldv  = ws + 5112336;

  hipMemsetAsync(ssum, 0, 544 * sizeof(float), stream);

  gemm_f32<<<dim3(NR / BM, 2), blk, 0, stream>>>(x1, W1, nullptr, XW,        NR, HID, DIM1, DIM1, HID, 256);
  gemm_f32<<<dim3(NR / BM, 2), blk, 0, stream>>>(x2, W2, nullptr, XW + HID,  NR, HID, DIM2, DIM2, HID, 256);
  gemm_f32<<<dim3(NR / BM, 4), blk, 0, stream>>>(adj, XW, nullptr, H2, NR, 256, NR, NR, 256, 256);
  bnstats_kernel<<<512, blk, 0, stream>>>(H2, ssum, ssq);
  mulv_kernel<<<NR / 4, blk, 0, stream>>>(H2, ssum, ssq,
                                          gamma1, beta1, Wmu1, bmu1, Wlv1, blv1,
                                          gamma2, beta2, Wmu2, bmu2, Wlv2, blv2,
                                          pd_mu, pd_lv, zbuf);
  gating_kernel<<<NR / 64, 64, 0, stream>>>(zbuf, w_gate, w_noise, gates, imp, ldv);
  loss_kernel<<<1, 64, 0, stream>>>(imp, ldv, loss);
  gemm_f32<<<dim3(NR / BM, 1), blk, 0, stream>>>(zbuf, Wd1, nullptr, ZD,        NR, LATD, LATD, LATD, LATD, 128);
  gemm_f32<<<dim3(NR / BM, 1), blk, 0, stream>>>(zbuf, Wd2, nullptr, ZD + LATD, NR, LATD, LATD, LATD, LATD, 128);
  gemm_f32<<<dim3(NR / BM, 2), blk, 0, stream>>>(adj, ZD, nullptr, AZ, NR, 128, NR, NR, 128, 128);
  gemm_f32<<<dim3(NR / BM, (DIM1 + BN - 1) / BN), blk, 0, stream>>>(AZ,        Wfc1, bfc1, recon1, NR, DIM1, LATD, 128, DIM1, DIM1);
  gemm_f32<<<dim3(NR / BM, (DIM2 + BN - 1) / BN), blk, 0, stream>>>(AZ + LATD, Wfc2, bfc2, recon2, NR, DIM2, LATD, 128, DIM2, DIM2);
}

// Round 9
// 415.194 us; speedup vs baseline: 2.5821x; 2.5821x over previous
//
#include <hip/hip_runtime.h>
#include <math.h>

// Problem dims
#define NR    6144
#define DIM1  3000
#define DIM2  1000
#define HID   128
#define LATD  64
#define NEXP  16

typedef __bf16 bf16x8 __attribute__((ext_vector_type(8)));
typedef float  f32x4  __attribute__((ext_vector_type(4)));

// ================================================================
// f32 -> bf16 helpers
// ================================================================
__device__ __forceinline__ unsigned short f2bf_rne(float x) {
  unsigned u = __float_as_uint(x);
  u += 0x7FFFu + ((u >> 16) & 1u);
  return (unsigned short)(u >> 16);
}
__device__ __forceinline__ void split2(float v, unsigned short& h, unsigned short& l) {
  h = f2bf_rne(v);
  float hf = __uint_as_float((unsigned)h << 16);
  l = f2bf_rne(v - hf);
}
__device__ __forceinline__ unsigned cvt_pk_bf16(float a, float b) {
  unsigned r;
  asm("v_cvt_pk_bf16_f32 %0, %1, %2" : "=v"(r) : "v"(a), "v"(b));
  return r;
}

// ================================================================
// 3-pass MFMA GEMM, B staged via global_load_lds from pre-assembled
// 16KB LDS-image blocks (hi slots0-3 / lo slots4-7, 128B rows,
// phys_slot = slot ^ (row&7)). bufB double-buffered: gloads issued
// after barrier2 into other parity -> cross NO barrier in flight,
// drained by barrier1 of s+1 (full MFMA-cluster window).
// A (f32) reg-staged + cvt_pk packed (r4-proven placement).
// ================================================================
template<bool ATOMIC>
__device__ __forceinline__ void gemm_body3(
    unsigned short* __restrict__ bufA,
    unsigned short* __restrict__ bufB0, unsigned short* __restrict__ bufB1,
    const float* __restrict__ A, const unsigned short* __restrict__ Bblk,
    float* __restrict__ C, int N, int lda, int ldc,
    int bm, int bn, int k0, int kend)
{
  const int tid  = threadIdx.x;
  const int lane = tid & 63;
  const int wave = tid >> 6;
  const int wm = wave >> 1, wn = wave & 1;
  const int lrow = lane & 15, kg = lane >> 4;
  const int nsteps = (kend - k0 + 31) >> 5;
  if (nsteps <= 0) return;

  f32x4 acc[4][4];
  #pragma unroll
  for (int f = 0; f < 4; ++f)
    #pragma unroll
    for (int g = 0; g < 4; ++g)
      #pragma unroll
      for (int j = 0; j < 4; ++j) acc[f][g][j] = 0.f;

  const int srow = tid >> 1;
  const int ks   = (tid & 1) * 16;
  const int s0   = (tid & 1) * 2;
  const float* aRow = A + (size_t)(bm + srow) * lda;
  const int rx = srow & 7;
  const int wa0 = srow * 64 + (((s0 + 0) ^ rx) * 8);
  const int wa1 = srow * 64 + (((s0 + 1) ^ rx) * 8);
  const int wa2 = srow * 64 + (((s0 + 4) ^ rx) * 8);
  const int wa3 = srow * 64 + (((s0 + 5) ^ rx) * 8);

  float va[16];   // named local array, direct use only (rule #20)

  #define LOAD_A(gk) {                                                  \
    const int kb = (gk) + ks;                                           \
    if (kb + 16 <= kend) {                                              \
      const float4* ap = (const float4*)(aRow + kb);                    \
      float4 f0 = ap[0], f1 = ap[1], f2 = ap[2], f3 = ap[3];            \
      va[0]=f0.x; va[1]=f0.y; va[2]=f0.z; va[3]=f0.w;                   \
      va[4]=f1.x; va[5]=f1.y; va[6]=f1.z; va[7]=f1.w;                   \
      va[8]=f2.x; va[9]=f2.y; va[10]=f2.z; va[11]=f2.w;                 \
      va[12]=f3.x; va[13]=f3.y; va[14]=f3.z; va[15]=f3.w;               \
    } else {                                                            \
      _Pragma("unroll")                                                 \
      for (int i = 0; i < 16; ++i) va[i] = (kb + i < kend) ? aRow[kb + i] : 0.f; \
    }                                                                   \
  }

  #define STAGE_B(gk, dst) {                                            \
    const unsigned short* _src = Bblk + ((size_t)((gk) >> 5)) * 8192 + wave * 2048 + lane * 8; \
    unsigned short* _d = (dst) + wave * 2048;                           \
    __builtin_amdgcn_global_load_lds((const __attribute__((address_space(1))) unsigned int*)(_src),        (__attribute__((address_space(3))) unsigned int*)(_d),        16, 0, 0); \
    __builtin_amdgcn_global_load_lds((const __attribute__((address_space(1))) unsigned int*)(_src + 512),  (__attribute__((address_space(3))) unsigned int*)(_d + 512),  16, 0, 0); \
    __builtin_amdgcn_global_load_lds((const __attribute__((address_space(1))) unsigned int*)(_src + 1024), (__attribute__((address_space(3))) unsigned int*)(_d + 1024), 16, 0, 0); \
    __builtin_amdgcn_global_load_lds((const __attribute__((address_space(1))) unsigned int*)(_src + 1536), (__attribute__((address_space(3))) unsigned int*)(_d + 1536), 16, 0, 0); \
  }

  LOAD_A(k0);
  STAGE_B(k0, bufB0);

  for (int s = 0; s < nsteps; ++s) {
    unsigned short* bCur = (s & 1) ? bufB1 : bufB0;
    unsigned short* bNxt = (s & 1) ? bufB0 : bufB1;

    // ---- pack A(s): counted vmcnt wait on A loads only ----
    unsigned hw[8], lw[8];
    #pragma unroll
    for (int i = 0; i < 8; ++i) {
      hw[i] = cvt_pk_bf16(va[2*i], va[2*i+1]);
      const float h0 = __uint_as_float(hw[i] << 16);
      const float h1 = __uint_as_float(hw[i] & 0xFFFF0000u);
      lw[i] = cvt_pk_bf16(va[2*i] - h0, va[2*i+1] - h1);
    }

    __syncthreads();   // barrier1: prev MFMA reads done; drains B(s) gloads
    *(uint4*)&bufA[wa0] = make_uint4(hw[0], hw[1], hw[2], hw[3]);
    *(uint4*)&bufA[wa1] = make_uint4(hw[4], hw[5], hw[6], hw[7]);
    *(uint4*)&bufA[wa2] = make_uint4(lw[0], lw[1], lw[2], lw[3]);
    *(uint4*)&bufA[wa3] = make_uint4(lw[4], lw[5], lw[6], lw[7]);
    __syncthreads();   // barrier2: bufA visible

    // ---- issue next step's A loads + B gloads (fly across MFMA cluster) ----
    if (s + 1 < nsteps) {
      LOAD_A(k0 + (s + 1) * 32);
      STAGE_B(k0 + (s + 1) * 32, bNxt);
    }

    // ---- fragments + MFMA ----
    bf16x8 afh[4], bfh[4], afl[4], bfl[4];
    #pragma unroll
    for (int f = 0; f < 4; ++f) {
      const int r = wm * 64 + f * 16 + lrow;
      afh[f] = *(const bf16x8*)&bufA[r * 64 + ((kg ^ (r & 7)) * 8)];
      afl[f] = *(const bf16x8*)&bufA[r * 64 + (((4 + kg) ^ (r & 7)) * 8)];
      const int n = wn * 64 + f * 16 + lrow;
      bfh[f] = *(const bf16x8*)&bCur[n * 64 + ((kg ^ (n & 7)) * 8)];
      bfl[f] = *(const bf16x8*)&bCur[n * 64 + (((4 + kg) ^ (n & 7)) * 8)];
    }
    #pragma unroll
    for (int f = 0; f < 4; ++f)
      #pragma unroll
      for (int g = 0; g < 4; ++g) {
        acc[f][g] = __builtin_amdgcn_mfma_f32_16x16x32_bf16(afh[f], bfh[g], acc[f][g], 0, 0, 0);
        acc[f][g] = __builtin_amdgcn_mfma_f32_16x16x32_bf16(afl[f], bfh[g], acc[f][g], 0, 0, 0);
        acc[f][g] = __builtin_amdgcn_mfma_f32_16x16x32_bf16(afh[f], bfl[g], acc[f][g], 0, 0, 0);
      }
  }
  #undef LOAD_A
  #undef STAGE_B

  #pragma unroll
  for (int f = 0; f < 4; ++f) {
    #pragma unroll
    for (int g = 0; g < 4; ++g) {
      const int row0 = bm + wm * 64 + f * 16 + (lane >> 4) * 4;
      const int col  = bn + wn * 64 + g * 16 + (lane & 15);
      if (col < N) {
        #pragma unroll
        for (int j = 0; j < 4; ++j) {
          const size_t idx = (size_t)(row0 + j) * ldc + col;
          if (ATOMIC) atomicAdd(&C[idx], acc[f][g][j]);
          else        C[idx] = acc[f][g][j];
        }
      }
    }
  }
}

template<bool ATOMIC>
__global__ __launch_bounds__(256, 3) void gemm_mfma3(
    const float* __restrict__ A, const unsigned short* __restrict__ Bblk,
    int kblocks_per_tile, float* __restrict__ C,
    int N, int lda, int ldc, int K, int kchunk)
{
  __shared__ alignas(16) unsigned short bufA[8192];
  __shared__ alignas(16) unsigned short bufB0[8192];
  __shared__ alignas(16) unsigned short bufB1[8192];
  const unsigned short* Bt = Bblk + (size_t)blockIdx.y * kblocks_per_tile * 8192;
  const int k0 = blockIdx.z * kchunk;
  gemm_body3<ATOMIC>(bufA, bufB0, bufB1, A, Bt, C, N, lda, ldc,
                     blockIdx.x * 128, blockIdx.y * 128, k0, min(k0 + kchunk, K));
}

// fused encoder: job0 = x1@W1 -> XW[:,0:128], job1 = x2@W2 -> XW[:,128:256]
__global__ __launch_bounds__(256, 3) void gemm_enc3(
    const float* __restrict__ x1, const unsigned short* __restrict__ W1blk,
    const float* __restrict__ x2, const unsigned short* __restrict__ W2blk,
    float* __restrict__ XW)
{
  __shared__ alignas(16) unsigned short bufA[8192];
  __shared__ alignas(16) unsigned short bufB0[8192];
  __shared__ alignas(16) unsigned short bufB1[8192];
  if (blockIdx.y == 0) {
    const int k0 = blockIdx.z * 384;
    gemm_body3<true>(bufA, bufB0, bufB1, x1, W1blk, XW, HID, DIM1, 256,
                     blockIdx.x * 128, 0, k0, min(k0 + 384, DIM1));
  } else {
    const int k0 = blockIdx.z * 128;
    gemm_body3<true>(bufA, bufB0, bufB1, x2, W2blk, XW + HID, HID, DIM2, 256,
                     blockIdx.x * 128, 0, k0, min(k0 + 128, DIM2));
  }
}

// ================================================================
// Producer: assemble B into 16KB LDS-image blocks.
// in: f32 [K][ldin], cols [col0 + by*128, +128). Block b=(by,ks) holds
// rows n_local=c, k in [ks*32, +32): hi at c*64+((kl>>3)^(c&7))*8+(kl&7),
// lo at slot 4+(kl>>3). Zero-fill k >= K.
// ================================================================
__global__ __launch_bounds__(256) void pack_b_blocks(
    const float* __restrict__ in, int K, int ldin, int col0,
    unsigned short* __restrict__ out)
{
  __shared__ unsigned short img[8192];
  const int tid = threadIdx.x;
  const int ks  = blockIdx.x;
  const int k0  = ks * 32;
  const int c   = tid & 127;
  const int h   = tid >> 7;
  const int colg = col0 + blockIdx.y * 128 + c;
  #pragma unroll
  for (int i = 0; i < 16; ++i) {
    const int kl = h + 2 * i;
    const int k  = k0 + kl;
    const float v = (k < K) ? in[(size_t)k * ldin + colg] : 0.f;
    unsigned short hi, lo;
    split2(v, hi, lo);
    const int base = c * 64 + (kl & 7);
    img[base + (((kl >> 3) ^ (c & 7)) * 8)]       = hi;
    img[base + ((((kl >> 3) + 4) ^ (c & 7)) * 8)] = lo;
  }
  __syncthreads();
  const size_t ob = ((size_t)blockIdx.y * gridDim.x + ks) * 8192;
  const uint4* s4 = (const uint4*)img;
  uint4* o4 = (uint4*)(out + ob);
  #pragma unroll
  for (int i = 0; i < 4; ++i) o4[tid + i * 256] = s4[tid + i * 256];
}

// ================================================================
// 1-pass MFMA GEMM (r4 structure, reg-staged B) — for adj@ZD + recon
// ================================================================
template<bool ATOMIC>
__global__ __launch_bounds__(256, 3) void gemm_mfma1(
    const float* __restrict__ A,
    const unsigned short* __restrict__ BT,
    const float* __restrict__ bias,
    float* __restrict__ C,
    int M, int N, int K, int lda, int Kpad, int ldc, int kchunk)
{
  __shared__ alignas(16) unsigned short bufA[128 * 64];
  const int tid  = threadIdx.x;
  const int lane = tid & 63;
  const int wave = tid >> 6;
  const int wm = wave >> 1, wn = wave & 1;
  const int lrow = lane & 15, kg = lane >> 4;
  const int bm = blockIdx.x * 128;
  const int bn = blockIdx.y * 128;
  const int k0 = blockIdx.z * kchunk;
  const int kend = min(k0 + kchunk, K);
  const int nsteps = (kend - k0 + 31) >> 5;

  f32x4 acc[4][4];
  #pragma unroll
  for (int f = 0; f < 4; ++f)
    #pragma unroll
    for (int g = 0; g < 4; ++g)
      #pragma unroll
      for (int j = 0; j < 4; ++j) acc[f][g][j] = 0.f;

  const int srow = tid >> 1;
  const int ks   = (tid & 1) * 16;
  const int s0   = (tid & 1) * 2;
  const float* aRow = A + (size_t)(bm + srow) * lda;
  const int gn = bn + srow;
  const bool bvalid = gn < N;
  const unsigned short* bRowH = BT + (size_t)(bvalid ? gn : 0) * Kpad;
  const int rx = srow & 7;
  const int wa0 = srow * 64 + (((s0 + 0) ^ rx) * 8);
  const int wa1 = srow * 64 + (((s0 + 1) ^ rx) * 8);
  const int wa2 = srow * 64 + (((s0 + 4) ^ rx) * 8);
  const int wa3 = srow * 64 + (((s0 + 5) ^ rx) * 8);

  float va[16];
  uint4 bh0 = make_uint4(0,0,0,0), bh1 = bh0;

  #define LOAD_A1(gk) {                                                 \
    const int kb = (gk) + ks;                                           \
    if (kb + 16 <= kend) {                                              \
      const float4* ap = (const float4*)(aRow + kb);                    \
      float4 f0 = ap[0], f1 = ap[1], f2 = ap[2], f3 = ap[3];            \
      va[0]=f0.x; va[1]=f0.y; va[2]=f0.z; va[3]=f0.w;                   \
      va[4]=f1.x; va[5]=f1.y; va[6]=f1.z; va[7]=f1.w;                   \
      va[8]=f2.x; va[9]=f2.y; va[10]=f2.z; va[11]=f2.w;                 \
      va[12]=f3.x; va[13]=f3.y; va[14]=f3.z; va[15]=f3.w;               \
    } else {                                                            \
      _Pragma("unroll")                                                 \
      for (int i = 0; i < 16; ++i) va[i] = (kb + i < kend) ? aRow[kb + i] : 0.f; \
    }                                                                   \
  }
  #define LOAD_B1(gk) {                                                 \
    if (bvalid) {                                                       \
      const uint4* bp = (const uint4*)(bRowH + (gk) + ks);              \
      bh0 = bp[0]; bh1 = bp[1];                                         \
    }                                                                   \
  }

  LOAD_A1(k0);
  LOAD_B1(k0);

  for (int s = 0; s < nsteps; ++s) {
    unsigned hw[8];
    #pragma unroll
    for (int i = 0; i < 8; ++i) hw[i] = cvt_pk_bf16(va[2*i], va[2*i+1]);
    uint4 wb0 = bh0, wb1 = bh1;

    __syncthreads();
    *(uint4*)&bufA[wa0] = make_uint4(hw[0], hw[1], hw[2], hw[3]);
    *(uint4*)&bufA[wa1] = make_uint4(hw[4], hw[5], hw[6], hw[7]);
    *(uint4*)&bufA[wa2] = wb0;
    *(uint4*)&bufA[wa3] = wb1;
    __syncthreads();

    if (s + 1 < nsteps) {
      LOAD_A1(k0 + (s + 1) * 32);
      LOAD_B1(k0 + (s + 1) * 32);
    }

    bf16x8 afh[4], bfh[4];
    #pragma unroll
    for (int f = 0; f < 4; ++f) {
      const int r = wm * 64 + f * 16 + lrow;
      afh[f] = *(const bf16x8*)&bufA[r * 64 + ((kg ^ (r & 7)) * 8)];
      const int n = wn * 64 + f * 16 + lrow;
      bfh[f] = *(const bf16x8*)&bufA[n * 64 + (((4 + kg) ^ (n & 7)) * 8)];
    }
    #pragma unroll
    for (int f = 0; f < 4; ++f)
      #pragma unroll
      for (int g = 0; g < 4; ++g)
        acc[f][g] = __builtin_amdgcn_mfma_f32_16x16x32_bf16(afh[f], bfh[g], acc[f][g], 0, 0, 0);
  }
  #undef LOAD_A1
  #undef LOAD_B1

  #pragma unroll
  for (int f = 0; f < 4; ++f) {
    #pragma unroll
    for (int g = 0; g < 4; ++g) {
      const int row0 = bm + wm * 64 + f * 16 + (lane >> 4) * 4;
      const int col  = bn + wn * 64 + g * 16 + (lane & 15);
      if (col < N) {
        #pragma unroll
        for (int j = 0; j < 4; ++j) {
          const size_t idx = (size_t)(row0 + j) * ldc + col;
          if (ATOMIC) atomicAdd(&C[idx], acc[f][g][j]);
          else        C[idx] = acc[f][g][j] + (bias ? bias[col] : 0.f);
        }
      }
    }
  }
}

// ================================================================
// Transpose + hi/lo split (old layout): f32 [K][N] -> bf16 [N][Kpad]
// ================================================================
__global__ __launch_bounds__(256) void transpose_split(
    const float* __restrict__ in, unsigned short* __restrict__ out_hi,
    unsigned short* __restrict__ out_lo, int K, int N, int Kpad)
{
  __shared__ float tile[32][33];
  const int k0 = blockIdx.x * 32, n0 = blockIdx.y * 32;
  const int tx = threadIdx.x & 31, ty = threadIdx.x >> 5;
  #pragma unroll
  for (int r = 0; r < 4; ++r) {
    const int k = k0 + ty + r * 8;
    tile[ty + r * 8][tx] = (k < K && n0 + tx < N) ? in[(size_t)k * N + n0 + tx] : 0.f;
  }
  __syncthreads();
  #pragma unroll
  for (int r = 0; r < 4; ++r) {
    const int nn = ty + r * 8;
    const int n = n0 + nn, k = k0 + tx;
    if (n < N && k < Kpad) {
      unsigned short h, l;
      split2(tile[tx][nn], h, l);
      out_hi[(size_t)n * Kpad + k] = h;
      if (out_lo) out_lo[(size_t)n * Kpad + k] = l;
    }
  }
}

// ================================================================
// f32 tiled GEMM (fallback + small z@Wd)
// ================================================================
#define BM 64
#define BN 64
#define BK 16

__global__ __launch_bounds__(256) void gemm_f32(
    const float* __restrict__ A, const float* __restrict__ B,
    const float* __restrict__ bias, float* __restrict__ C,
    int M, int N, int K, int lda, int ldb, int ldc)
{
  __shared__ float At[BK][BM + 4];
  __shared__ float Bt[BK][BN + 4];
  const int tid = threadIdx.x;
  const int tx = tid & 15;
  const int ty = tid >> 4;
  const int bm = blockIdx.x * BM;
  const int bn = blockIdx.y * BN;

  float acc[4][4] = {};

  const int ar = tid >> 2;
  const int ak = (tid & 3) * 4;
  const int bk = tid >> 4;
  const int bc = (tid & 15) * 4;

  for (int k0 = 0; k0 < K; k0 += BK) {
    {
      float4 v = make_float4(0.f, 0.f, 0.f, 0.f);
      const int gr = bm + ar;
      const int gk = k0 + ak;
      if (gr < M && gk < K) {
        const float* p = &A[(size_t)gr * lda];
        if (gk + 3 < K) v = *reinterpret_cast<const float4*>(&p[gk]);
        else {
          v.x = p[gk];
          if (gk + 1 < K) v.y = p[gk + 1];
          if (gk + 2 < K) v.z = p[gk + 2];
        }
      }
      At[ak + 0][ar] = v.x; At[ak + 1][ar] = v.y;
      At[ak + 2][ar] = v.z; At[ak + 3][ar] = v.w;
    }
    {
      float4 v = make_float4(0.f, 0.f, 0.f, 0.f);
      const int gk = k0 + bk;
      const int gc = bn + bc;
      if (gk < K) {
        const float* p = &B[(size_t)gk * ldb];
        if (gc + 3 < N) v = *reinterpret_cast<const float4*>(&p[gc]);
        else {
          if (gc     < N) v.x = p[gc];
          if (gc + 1 < N) v.y = p[gc + 1];
          if (gc + 2 < N) v.z = p[gc + 2];
        }
      }
      *reinterpret_cast<float4*>(&Bt[bk][bc]) = v;
    }
    __syncthreads();
    #pragma unroll
    for (int kk = 0; kk < BK; ++kk) {
      float4 a4 = *reinterpret_cast<const float4*>(&At[kk][ty * 4]);
      float4 b4 = *reinterpret_cast<const float4*>(&Bt[kk][tx * 4]);
      float av[4] = {a4.x, a4.y, a4.z, a4.w};
      float bv[4] = {b4.x, b4.y, b4.z, b4.w};
      #pragma unroll
      for (int i = 0; i < 4; ++i)
        #pragma unroll
        for (int j = 0; j < 4; ++j)
          acc[i][j] = fmaf(av[i], bv[j], acc[i][j]);
    }
    __syncthreads();
  }

  #pragma unroll
  for (int i = 0; i < 4; ++i) {
    const int row = bm + ty * 4 + i;
    if (row >= M) continue;
    #pragma unroll
    for (int j = 0; j < 4; ++j) {
      const int col = bn + tx * 4 + j;
      if (col < N) {
        float v = acc[i][j];
        if (bias) v += bias[col];
        C[(size_t)row * ldc + col] = v;
      }
    }
  }
}

// ================================================================
// BN stats / fused heads+PoE / gating / loss  (verified round 2)
// ================================================================
__global__ __launch_bounds__(256) void bnstats_kernel(
    const float* __restrict__ H2, float* __restrict__ ssum, float* __restrict__ ssq)
{
  const int c = threadIdx.x;
  const int r0 = blockIdx.x * 12;
  float s = 0.f, q = 0.f;
  #pragma unroll
  for (int i = 0; i < 12; ++i) {
    float v = H2[(size_t)(r0 + i) * 256 + c];
    s += v;
    q = fmaf(v, v, q);
  }
  atomicAdd(&ssum[c], s);
  atomicAdd(&ssq[c], q);
}

__global__ __launch_bounds__(256) void mulv_kernel(
    const float* __restrict__ H2, const float* __restrict__ ssum, const float* __restrict__ ssq,
    const float* __restrict__ g1, const float* __restrict__ b1,
    const float* __restrict__ Wmu1, const float* __restrict__ bmu1,
    const float* __restrict__ Wlv1, const float* __restrict__ blv1,
    const float* __restrict__ g2, const float* __restrict__ b2,
    const float* __restrict__ Wmu2, const float* __restrict__ bmu2,
    const float* __restrict__ Wlv2, const float* __restrict__ blv2,
    float* __restrict__ pd_mu_out, float* __restrict__ pd_lv_out, float* __restrict__ z_out)
{
  __shared__ float hn[4][256];
  const int tid = threadIdx.x;
  const int r0 = blockIdx.x * 4;

  for (int idx = tid; idx < 1024; idx += 256) {
    const int rr = idx >> 8;
    const int c  = idx & 255;
    const float mean = ssum[c] * (1.0f / 6144.0f);
    const float var  = ssq[c] * (1.0f / 6144.0f) - mean * mean;
    const float rstd = 1.0f / sqrtf(var + 1e-5f);
    const float gamma = (c < HID) ? g1[c] : g2[c - HID];
    const float beta  = (c < HID) ? b1[c] : b2[c - HID];
    const float v = H2[(size_t)(r0 + rr) * 256 + c];
    hn[rr][c] = (v - mean) * rstd * gamma + beta;
  }
  __syncthreads();

  const int rr = tid >> 6;
  const int j  = tid & 63;
  float mu1 = bmu1[j], lv1 = blv1[j], mu2 = bmu2[j], lv2 = blv2[j];
  #pragma unroll 4
  for (int k = 0; k < HID; ++k) {
    const float h1 = hn[rr][k];
    const float h2 = hn[rr][HID + k];
    mu1 = fmaf(h1, Wmu1[k * LATD + j], mu1);
    lv1 = fmaf(h1, Wlv1[k * LATD + j], lv1);
    mu2 = fmaf(h2, Wmu2[k * LATD + j], mu2);
    lv2 = fmaf(h2, Wlv2[k * LATD + j], lv2);
  }
  const float var1 = expf(lv1) + 1e-8f;
  const float var2 = expf(lv2) + 1e-8f;
  const float T1 = 1.0f / (var1 + 1e-8f);
  const float T2 = 1.0f / (var2 + 1e-8f);
  const float denom = T1 + T2;
  const float pmu = (mu1 * T1 + mu2 * T2) / denom;
  const float plv = logf(1.0f / denom + 1e-8f);
  const size_t o = (size_t)(r0 + rr) * LATD + j;
  pd_mu_out[o] = pmu;
  pd_lv_out[o] = plv;
  z_out[o]     = pmu;
}

__device__ __forceinline__ unsigned rotl32(unsigned x, int r) {
  return (x << r) | (x >> (32 - r));
}

__device__ float threefry_normal(unsigned i) {
  const unsigned ks0 = 0u;
  const unsigned ks1 = 42u;
  const unsigned ks2 = 0x1BD11BDAu ^ 0u ^ 42u;
  unsigned x0 = 0u + ks0;
  unsigned x1 = i + ks1;

  #define TF_ROUND(r) { x0 += x1; x1 = rotl32(x1, r); x1 ^= x0; }
  TF_ROUND(13) TF_ROUND(15) TF_ROUND(26) TF_ROUND(6)
  x0 += ks1; x1 += ks2 + 1u;
  TF_ROUND(17) TF_ROUND(29) TF_ROUND(16) TF_ROUND(24)
  x0 += ks2; x1 += ks0 + 2u;
  TF_ROUND(13) TF_ROUND(15) TF_ROUND(26) TF_ROUND(6)
  x0 += ks0; x1 += ks1 + 3u;
  TF_ROUND(17) TF_ROUND(29) TF_ROUND(16) TF_ROUND(24)
  x0 += ks1; x1 += ks2 + 4u;
  TF_ROUND(13) TF_ROUND(15) TF_ROUND(26) TF_ROUND(6)
  x0 += ks2; x1 += ks0 + 5u;
  #undef TF_ROUND

  const unsigned bits = x0 ^ x1;

  const unsigned fb = (bits >> 9) | 0x3F800000u;
  const float u01 = __uint_as_float(fb) - 1.0f;
  const float minval = -0.99999994f;
  float u = fmaf(u01, 2.0f, minval);
  u = fmaxf(minval, u);

  float w = -log1pf(-u * u);
  float p;
  if (w < 5.0f) {
    w = w - 2.5f;
    p = 2.81022636e-08f;
    p = fmaf(p, w, 3.43273939e-07f);
    p = fmaf(p, w, -3.5233877e-06f);
    p = fmaf(p, w, -4.39150654e-06f);
    p = fmaf(p, w, 0.00021858087f);
    p = fmaf(p, w, -0.00125372503f);
    p = fmaf(p, w, -0.00417768164f);
    p = fmaf(p, w, 0.246640727f);
    p = fmaf(p, w, 1.50140941f);
  } else {
    w = sqrtf(w) - 3.0f;
    p = -0.000200214257f;
    p = fmaf(p, w, 0.000100950558f);
    p = fmaf(p, w, 0.00134934322f);
    p = fmaf(p, w, -0.00367342844f);
    p = fmaf(p, w, 0.00573950773f);
    p = fmaf(p, w, -0.0076224613f);
    p = fmaf(p, w, 0.00943887047f);
    p = fmaf(p, w, 1.00167406f);
    p = fmaf(p, w, 2.83297682f);
  }
  return 1.4142135f * (p * u);
}

__global__ __launch_bounds__(64) void gating_kernel(
    const float* __restrict__ z, const float* __restrict__ w_gate,
    const float* __restrict__ w_noise, float* __restrict__ gates_out,
    float* __restrict__ importance, float* __restrict__ loadv)
{
  __shared__ float zt[64][65];
  __shared__ float wg[64][16];
  __shared__ float wn[64][16];
  __shared__ float imp_s[16];
  __shared__ float load_s[16];

  const int tid = threadIdx.x;
  const int r0 = blockIdx.x * 64;

  for (int idx = tid; idx < 1024; idx += 64) {
    wg[idx >> 4][idx & 15] = w_gate[idx];
    wn[idx >> 4][idx & 15] = w_noise[idx];
  }
  for (int idx = tid; idx < 4096; idx += 64) {
    const int rr = idx >> 6, c = idx & 63;
    zt[rr][c] = z[(size_t)(r0 + rr) * 64 + c];
  }
  if (tid < 16) { imp_s[tid] = 0.f; load_s[tid] = 0.f; }
  __syncthreads();

  const int r = r0 + tid;
  float clean[16], noisy[16], stdv[16];
  #pragma unroll
  for (int e = 0; e < NEXP; ++e) {
    float c = 0.f, n = 0.f;
    #pragma unroll 8
    for (int k = 0; k < 64; ++k) {
      const float zv = zt[tid][k];
      c = fmaf(zv, wg[k][e], c);
      n = fmaf(zv, wn[k][e], n);
    }
    clean[e] = c;
    const float sp = fmaxf(n, 0.f) + log1pf(expf(-fabsf(n)));
    stdv[e] = sp + 0.01f;
    const float eps = threefry_normal((unsigned)r * 16u + (unsigned)e);
    noisy[e] = fmaf(eps, stdv[e], c);
  }

  float v0 = -1e30f, v1 = -1e30f, v2 = -1e30f;
  int i0 = 0, i1 = 0;
  #pragma unroll
  for (int e = 0; e < NEXP; ++e) {
    const float v = noisy[e];
    if (v > v0)      { v2 = v1; v1 = v0; i1 = i0; v0 = v; i0 = e; }
    else if (v > v1) { v2 = v1; v1 = v; i1 = e; }
    else if (v > v2) { v2 = v; }
  }

  const float e1 = expf(v1 - v0);
  const float inv = 1.0f / (1.0f + e1);
  const float g0 = inv;
  const float g1v = e1 * inv;

  float lacc[16];
  #pragma unroll
  for (int e = 0; e < NEXP; ++e) {
    const float gv = (e == i0) ? g0 : ((e == i1) ? g1v : 0.f);
    gates_out[(size_t)r * NEXP + e] = gv;
    const float thr = (noisy[e] > v2) ? v2 : v1;
    const float x = (clean[e] - thr) / stdv[e];
    lacc[e] = 0.5f * erfcf(-0.70710678f * x);
  }
  atomicAdd(&imp_s[i0], g0);
  atomicAdd(&imp_s[i1], g1v);
  #pragma unroll
  for (int e = 0; e < NEXP; ++e) atomicAdd(&load_s[e], lacc[e]);
  __syncthreads();
  if (tid < 16) {
    atomicAdd(&importance[tid], imp_s[tid]);
    atomicAdd(&loadv[tid], load_s[tid]);
  }
}

__global__ void loss_kernel(const float* __restrict__ imp, const float* __restrict__ ld,
                            float* __restrict__ out)
{
  if (threadIdx.x == 0 && blockIdx.x == 0) {
    float mi = 0.f, ml = 0.f;
    for (int e = 0; e < NEXP; ++e) { mi += imp[e]; ml += ld[e]; }
    mi *= (1.0f / 16.0f);
    ml *= (1.0f / 16.0f);
    float vi = 0.f, vl = 0.f;
    for (int e = 0; e < NEXP; ++e) {
      const float di = imp[e] - mi;
      const float dl = ld[e] - ml;
      vi = fmaf(di, di, vi);
      vl = fmaf(dl, dl, vl);
    }
    vi *= (1.0f / 15.0f);
    vl *= (1.0f / 15.0f);
    out[0] = vi / (mi * mi + 1e-10f) + vl / (ml * ml + 1e-10f);
  }
}

// ================================================================
extern "C" void kernel_launch(void* const* d_in, const int* in_sizes, int n_in,
                              void* d_out, int out_size, void* d_ws, size_t ws_size,
                              hipStream_t stream)
{
  const float* x1     = (const float*)d_in[0];
  const float* x2     = (const float*)d_in[1];
  const float* adj    = (const float*)d_in[2];
  const float* W1     = (const float*)d_in[3];
  const float* gamma1 = (const float*)d_in[4];
  const float* beta1  = (const float*)d_in[5];
  const float* Wmu1   = (const float*)d_in[6];
  const float* bmu1   = (const float*)d_in[7];
  const float* Wlv1   = (const float*)d_in[8];
  const float* blv1   = (const float*)d_in[9];
  const float* W2     = (const float*)d_in[10];
  const float* gamma2 = (const float*)d_in[11];
  const float* beta2  = (const float*)d_in[12];
  const float* Wmu2   = (const float*)d_in[13];
  const float* bmu2   = (const float*)d_in[14];
  const float* Wlv2   = (const float*)d_in[15];
  const float* blv2   = (const float*)d_in[16];
  const float* w_gate = (const float*)d_in[17];
  const float* w_noise= (const float*)d_in[18];
  const float* Wd1    = (const float*)d_in[19];
  const float* Wfc1   = (const float*)d_in[20];
  const float* bfc1   = (const float*)d_in[21];
  const float* Wd2    = (const float*)d_in[22];
  const float* Wfc2   = (const float*)d_in[23];
  const float* bfc2   = (const float*)d_in[24];

  float* out = (float*)d_out;
  float* recon1 = out;
  float* recon2 = out + (size_t)NR * DIM1;
  float* pd_mu  = recon2 + (size_t)NR * DIM2;
  float* pd_lv  = pd_mu + (size_t)NR * LATD;
  float* gates  = pd_lv + (size_t)NR * LATD;
  float* loss   = gates + (size_t)NR * NEXP;

  // ---------------- fast-path workspace layout (bytes) ----------------
  char* wsb = (char*)d_ws;
  const size_t o_XW   = 0;                      // f32 [6144][256]
  const size_t o_H2   = o_XW   + 6291456;       // f32 [6144][256]
  const size_t o_z    = o_H2   + 6291456;       // f32 [6144][64]
  const size_t o_ZD   = o_z    + 1572864;       // f32 [6144][128]
  const size_t o_AZ   = o_ZD   + 3145728;       // f32 [6144][128]
  const size_t o_XWB  = o_AZ   + 3145728;       // XW blocks: 2 tiles x 192 x 16KB = 6291456
  const size_t o_W1B  = o_XWB  + 6291456;       // W1 blocks: 94 x 16KB = 1540096
  const size_t o_W2B  = o_W1B  + 1540096;       // W2 blocks: 32 x 16KB = 524288
  const size_t o_ZDTh = o_W2B  + 524288;        // bf16 [128][6144] (old layout)
  const size_t o_F1Th = o_ZDTh + 1572864;       // bf16 [3000][64]
  const size_t o_F2Th = o_F1Th + 384000;        // bf16 [1000][64]
  const size_t o_stat = o_F2Th + 128000;        // 544 f32
  const size_t need   = o_stat + 2176;

  const dim3 blk(256);

  if (ws_size >= need) {
    // ================= fast path: bf16 MFMA =================
    float* XW   = (float*)(wsb + o_XW);
    float* H2   = (float*)(wsb + o_H2);
    float* zbuf = (float*)(wsb + o_z);
    float* ZD   = (float*)(wsb + o_ZD);
    float* AZ   = (float*)(wsb + o_AZ);
    unsigned short* XWB  = (unsigned short*)(wsb + o_XWB);
    unsigned short* W1B  = (unsigned short*)(wsb + o_W1B);
    unsigned short* W2B  = (unsigned short*)(wsb + o_W2B);
    unsigned short* ZDTh = (unsigned short*)(wsb + o_ZDTh);
    unsigned short* F1Th = (unsigned short*)(wsb + o_F1Th);
    unsigned short* F2Th = (unsigned short*)(wsb + o_F2Th);
    float* ssum = (float*)(wsb + o_stat);
    float* ssq  = ssum + 256;
    float* imp  = ssq + 256;
    float* ldv  = imp + 16;

    hipMemsetAsync(XW, 0, 6291456 * 2, stream);          // XW + H2
    hipMemsetAsync(AZ, 0, 3145728, stream);
    hipMemsetAsync(ssum, 0, 2176, stream);

    // pre-assemble weight B blocks + old-layout decoder transposes
    pack_b_blocks<<<dim3(94, 1), blk, 0, stream>>>(W1, DIM1, HID, 0, W1B);
    pack_b_blocks<<<dim3(32, 1), blk, 0, stream>>>(W2, DIM2, HID, 0, W2B);
    transpose_split<<<dim3(2, 94), blk, 0, stream>>>(Wfc1, F1Th, nullptr, LATD, DIM1, 64);
    transpose_split<<<dim3(2, 32), blk, 0, stream>>>(Wfc2, F2Th, nullptr, LATD, DIM2, 64);

    // fused encoder: XW = [x1@W1 | x2@W2]  (3-pass, split-K=8)
    gemm_enc3<<<dim3(48, 2, 8), blk, 0, stream>>>(x1, W1B, x2, W2B, XW);

    // assemble XW^T into B blocks
    pack_b_blocks<<<dim3(192, 2), blk, 0, stream>>>(XW, NR, 256, 0, XWB);

    // H2 = adj @ XW  (3-pass, split-K=8)
    gemm_mfma3<true><<<dim3(48, 2, 8), blk, 0, stream>>>(
        adj, XWB, 192, H2, 256, NR, 256, NR, 768);

    bnstats_kernel<<<512, blk, 0, stream>>>(H2, ssum, ssq);
    mulv_kernel<<<NR / 4, blk, 0, stream>>>(H2, ssum, ssq,
        gamma1, beta1, Wmu1, bmu1, Wlv1, blv1,
        gamma2, beta2, Wmu2, bmu2, Wlv2, blv2,
        pd_mu, pd_lv, zbuf);

    gating_kernel<<<NR / 64, 64, 0, stream>>>(zbuf, w_gate, w_noise, gates, imp, ldv);
    loss_kernel<<<1, 64, 0, stream>>>(imp, ldv, loss);

    // decoders
    gemm_f32<<<dim3(96, 1), blk, 0, stream>>>(zbuf, Wd1, nullptr, ZD,        NR, LATD, LATD, LATD, LATD, 128);
    gemm_f32<<<dim3(96, 1), blk, 0, stream>>>(zbuf, Wd2, nullptr, ZD + LATD, NR, LATD, LATD, LATD, LATD, 128);
    transpose_split<<<dim3(192, 4), blk, 0, stream>>>(ZD, ZDTh, nullptr, NR, 128, NR);
    gemm_mfma1<true><<<dim3(48, 1, 16), blk, 0, stream>>>(
        adj, ZDTh, nullptr, AZ, NR, 128, NR, NR, NR, 128, 384);
    gemm_mfma1<false><<<dim3(48, 24, 1), blk, 0, stream>>>(
        AZ, F1Th, bfc1, recon1, NR, DIM1, LATD, 128, 64, DIM1, 64);
    gemm_mfma1<false><<<dim3(48, 8, 1), blk, 0, stream>>>(
        AZ + LATD, F2Th, bfc2, recon2, NR, DIM2, LATD, 128, 64, DIM2, 64);
    return;
  }

  // ================= fallback: verified f32 path =================
  float* ws   = (float*)d_ws;
  float* XW   = ws;
  float* H2   = ws + 1572864;
  float* zbuf = ws + 3145728;
  float* ZD   = ws + 3538944;
  float* AZ   = ws + 4325376;
  float* ssum = ws + 5111808;
  float* ssq  = ws + 5112064;
  float* imp  = ws + 5112320;
  float* ldv  = ws + 5112336;

  hipMemsetAsync(ssum, 0, 544 * sizeof(float), stream);

  gemm_f32<<<dim3(NR / BM, 2), blk, 0, stream>>>(x1, W1, nullptr, XW,        NR, HID, DIM1, DIM1, HID, 256);
  gemm_f32<<<dim3(NR / BM, 2), blk, 0, stream>>>(x2, W2, nullptr, XW + HID,  NR, HID, DIM2, DIM2, HID, 256);
  gemm_f32<<<dim3(NR / BM, 4), blk, 0, stream>>>(adj, XW, nullptr, H2, NR, 256, NR, NR, 256, 256);
  bnstats_kernel<<<512, blk, 0, stream>>>(H2, ssum, ssq);
  mulv_kernel<<<NR / 4, blk, 0, stream>>>(H2, ssum, ssq,
                                          gamma1, beta1, Wmu1, bmu1, Wlv1, blv1,
                                          gamma2, beta2, Wmu2, bmu2, Wlv2, blv2,
                                          pd_mu, pd_lv, zbuf);
  gating_kernel<<<NR / 64, 64, 0, stream>>>(zbuf, w_gate, w_noise, gates, imp, ldv);
  loss_kernel<<<1, 64, 0, stream>>>(imp, ldv, loss);
  gemm_f32<<<dim3(NR / BM, 1), blk, 0, stream>>>(zbuf, Wd1, nullptr, ZD,        NR, LATD, LATD, LATD, LATD, 128);
  gemm_f32<<<dim3(NR / BM, 1), blk, 0, stream>>>(zbuf, Wd2, nullptr, ZD + LATD, NR, LATD, LATD, LATD, LATD, 128);
  gemm_f32<<<dim3(NR / BM, 2), blk, 0, stream>>>(adj, ZD, nullptr, AZ, NR, 128, NR, NR, 128, 128);
  gemm_f32<<<dim3(NR / BM, (DIM1 + BN - 1) / BN), blk, 0, stream>>>(AZ,        Wfc1, bfc1, recon1, NR, DIM1, LATD, 128, DIM1, DIM1);
  gemm_f32<<<dim3(NR / BM, (DIM2 + BN - 1) / BN), blk, 0, stream>>>(AZ + LATD, Wfc2, bfc2, recon2, NR, DIM2, LATD, 128, DIM2, DIM2);
}